// Round 4
// baseline (5865.299 us; speedup 1.0000x reference)
//
#include <hip/hip_runtime.h>
#include <cstdint>

typedef _Float16 f16x8 __attribute__((ext_vector_type(8)));
typedef float    f32x4 __attribute__((ext_vector_type(4)));
typedef unsigned int u32;
typedef u32      u32x4 __attribute__((ext_vector_type(4)));

#define BB 64
#define TT 256
#define EE 512
#define UU 1024
#define NN 3072   // 3*U

#define MFMA16(a, b, c) __builtin_amdgcn_mfma_f32_16x16x32_f16((a), (b), (c), 0, 0, 0)

// ---------------- prep: Wh -> f16 MFMA B-fragment layout ----------------
// WhF[((nt*3+g)*32 + kb)*64 + lane][jj] = f16(Wh[kb*32 + quad*8 + jj][g*1024 + nt*16 + l16])
__global__ __launch_bounds__(256) void prep_whf(const float* __restrict__ Wh,
                                                _Float16* __restrict__ WhF) {
    int tid  = blockIdx.x * 256 + threadIdx.x;
    int col8 = tid % 384;
    int k    = tid / 384;
    int kb = k >> 5, quad = (k >> 3) & 3, jj = k & 7;
    const float* src = Wh + (long)k * NN + col8 * 8;
#pragma unroll
    for (int i = 0; i < 8; i++) {
        int n   = col8 * 8 + i;
        int g   = n >> 10;
        int nl  = n & 1023;
        int jc  = nl >> 4, l16 = nl & 15;
        int lane = quad * 16 + l16;
        WhF[((((jc * 3 + g) * 32 + kb) * 64 + lane) << 3) + jj] = (_Float16)src[i];
    }
}

// h0 -> tagged u32 words (tag = 0 in high 16 bits), slot 0
__global__ __launch_bounds__(256) void prep_h0(const float* __restrict__ h0,
                                               u32* __restrict__ hbuf) {
    int i = blockIdx.x * 256 + threadIdx.x;      // 0..65535
    unsigned short hv = __builtin_bit_cast(unsigned short, (_Float16)h0[i]);
    hbuf[i] = (u32)hv;                           // tag 0
}

// ---------------- embed + input projection GEMM (f16 MFMA) ----------------
__global__ __launch_bounds__(256) void proj_kernel(
    const int* __restrict__ tokens, const float* __restrict__ emb,
    const float* __restrict__ Wx, const float* __restrict__ bx,
    _Float16* __restrict__ xproj) {
    int tid  = threadIdx.x;
    int wave = tid >> 6, lane = tid & 63, quad = lane >> 4, l16 = lane & 15;
    int bm = blockIdx.x * 64;
    int bn = blockIdx.y * 128;
    int wm = (wave & 1) * 32, wn = (wave >> 1) * 64;

    int row0 = bm + wm + l16;
    const float* a0p = emb + (long)tokens[row0] * EE;
    const float* a1p = emb + (long)tokens[row0 + 16] * EE;

    f32x4 acc[2][4];
#pragma unroll
    for (int mt = 0; mt < 2; mt++)
#pragma unroll
        for (int nt = 0; nt < 4; nt++) { f32x4 z = {0.f, 0.f, 0.f, 0.f}; acc[mt][nt] = z; }

#pragma unroll 2
    for (int k0 = 0; k0 < EE; k0 += 32) {
        int ka = k0 + quad * 8;
        f16x8 afr[2];
        {
            const float4* p = (const float4*)(a0p + ka);
            float4 x0 = p[0], x1 = p[1];
            afr[0][0] = (_Float16)x0.x; afr[0][1] = (_Float16)x0.y;
            afr[0][2] = (_Float16)x0.z; afr[0][3] = (_Float16)x0.w;
            afr[0][4] = (_Float16)x1.x; afr[0][5] = (_Float16)x1.y;
            afr[0][6] = (_Float16)x1.z; afr[0][7] = (_Float16)x1.w;
        }
        {
            const float4* p = (const float4*)(a1p + ka);
            float4 x0 = p[0], x1 = p[1];
            afr[1][0] = (_Float16)x0.x; afr[1][1] = (_Float16)x0.y;
            afr[1][2] = (_Float16)x0.z; afr[1][3] = (_Float16)x0.w;
            afr[1][4] = (_Float16)x1.x; afr[1][5] = (_Float16)x1.y;
            afr[1][6] = (_Float16)x1.z; afr[1][7] = (_Float16)x1.w;
        }
        f16x8 bfr[4];
#pragma unroll
        for (int nt = 0; nt < 4; nt++) {
            const float* bp = Wx + (long)ka * NN + (bn + wn + nt * 16 + l16);
#pragma unroll
            for (int jj = 0; jj < 8; jj++) bfr[nt][jj] = (_Float16)bp[(long)jj * NN];
        }
#pragma unroll
        for (int mt = 0; mt < 2; mt++)
#pragma unroll
            for (int nt = 0; nt < 4; nt++)
                acc[mt][nt] = MFMA16(afr[mt], bfr[nt], acc[mt][nt]);
    }
#pragma unroll
    for (int mt = 0; mt < 2; mt++) {
        int rowbase = bm + wm + mt * 16 + quad * 4;
#pragma unroll
        for (int nt = 0; nt < 4; nt++) {
            int col = bn + wn + nt * 16 + l16;
            float bias = bx[col];
#pragma unroll
            for (int r = 0; r < 4; r++) {
                int i = rowbase + r;
                int b = i >> 8, t = i & 255;
                xproj[((long)t * BB + b) * NN + col] = (_Float16)(acc[mt][nt][r] + bias);
            }
        }
    }
}

// ---------------- persistent GRU recurrence: batch-partitioned domains ----------------
// R6: the GRU recurrence is independent across batch rows -> partition B=64
// into 4 DOMAINS of 16 rows. A domain's 8 WGs exchange only a 16x1024 h
// block (32KB payload / 64KB tagged), not the full 128KB: coherent-fabric
// traffic drops from R3/R4's 8-16MB/step to 2MB/step -- the quantity R2-R4
// showed to be the real cost.
//  - 32 WGs x 512 thr. WG = (domain d = wg>>3, u-slice s = wg&7 of 128 cols).
//    Wave k owns 16-col tile nt = s*8+k: 96 weight frags register-resident
//    (64 AGPR-pinned + 32 VGPR-pinned; R2-proven pattern).
//  - Sync fused into data (R4 protocol, logic proven; its failure was VGPR
//    spill at a 256-reg window): tagged u32 h words (hi16=step, lo16=f16 h),
//    fire-and-forget sc0sc1 stores, consumers load+verify+retry. Window here
//    is only 8 dwordx4/thread = 32 VGPRs -> spill hazard structurally gone.
//  - Consumers stage the 64KB tagged block ONCE per WG into LDS (strip tags,
//    XOR-swizzled to bank-conflict floor), 8 waves share it: 8x fewer
//    coherent reads than per-wave loading.
//  - Race/livelock-free (R4 induction): reads precede writes within a step;
//    tag-equality + 2 slots => a slot is overwritten only after every
//    domain reader certified (via its next-step tags) that it finished
//    reading it. Replay-safe: every cell rewritten every parity step.
//  - No flags, no atomics, no fences, no XCD-placement assumptions (G16-safe).
__global__ __launch_bounds__(512, 1) void gru_kernel(
    const _Float16* __restrict__ xproj,    // [T][B][3U]
    const _Float16* __restrict__ WhF,      // fragment layout
    const float* __restrict__ hidden,      // [B][U] fp32 h0
    const float* __restrict__ bh,          // [3U]
    u32* __restrict__ hbuf,                // [2][B][U] tagged h words
    float* __restrict__ out) {             // [B][T][U] ++ [B][U]
    __shared__ char ldsA[2][32768];        // double-buffered 16x1024 f16 A-block
    int tid  = threadIdx.x;
    int wave = tid >> 6, lane = tid & 63, quad = lane >> 4, l16 = lane & 15;
    int wg = blockIdx.x;                   // 0..31
    int d  = wg >> 3;                      // domain: batch rows [16d,16d+16)
    int s  = wg & 7;                       // u-slice of 128 cols
    int ntile = s * 8 + wave;              // this wave's 16-col u-tile (0..63)
    int u0 = ntile * 16;
    int r0 = d * 16;

    // ---- weights: 96 frags/wave, register-resident (64 AGPR + 32 VGPR) ----
    const f16x8* WF = (const f16x8*)WhF + (long)ntile * 96 * 64 + lane;
    f16x8 w[96];                           // w[g*32+kb], g=0:z 1:r 2:cand
#pragma unroll
    for (int i = 0; i < 96; i++) w[i] = WF[(long)i * 64];
#pragma unroll
    for (int i = 0; i < 64; i++) asm volatile("" : "+a"(w[i]));
#pragma unroll
    for (int i = 64; i < 96; i++) asm volatile("" : "+v"(w[i]));

    float bhz = bh[u0 + l16], bhr = bh[UU + u0 + l16], bhh = bh[2 * UU + u0 + l16];

    float hold[4];
#pragma unroll
    for (int r = 0; r < 4; r++)
        hold[r] = hidden[(long)(r0 + quad * 4 + r) * UU + u0 + l16];

    // consumer-load mapping: thread -> (row crow, K-block cj), 128B contiguous
    int crow = tid >> 5;                   // 0..15
    int cj   = tid & 31;                   // K-block = 32 u-values
    const u32* gsrc0 = hbuf + (long)(r0 + crow) * UU + cj * 32;

#pragma unroll 1
    for (int t = 0; t < TT; t++) {
        // ---- x loads: issued here (can't sink past the "memory" asm below);
        //      waits land at first use (epilogue) -> latency fully hidden ----
        float xz[4], xr[4], xh[4];
        {
            const _Float16* xp = xproj + (long)t * BB * NN + u0 + l16;
#pragma unroll
            for (int r = 0; r < 4; r++) {
                const _Float16* p = xp + (long)(r0 + quad * 4 + r) * NN;
                xz[r] = (float)p[0]; xr[r] = (float)p[UU]; xh[r] = (float)p[2 * UU];
            }
        }

        // ---- tagged A-block load: 8 dwordx4/thread, verify tags, retry ----
        const u32* gp = gsrc0 + (long)(t & 1) * (BB * UU);
        u32x4 hw[8];
        unsigned expect = (unsigned)t << 16;
        for (;;) {
            asm volatile(
                "global_load_dwordx4 %0, %8, off sc0 sc1\n\t"
                "global_load_dwordx4 %1, %8, off offset:16 sc0 sc1\n\t"
                "global_load_dwordx4 %2, %8, off offset:32 sc0 sc1\n\t"
                "global_load_dwordx4 %3, %8, off offset:48 sc0 sc1\n\t"
                "global_load_dwordx4 %4, %8, off offset:64 sc0 sc1\n\t"
                "global_load_dwordx4 %5, %8, off offset:80 sc0 sc1\n\t"
                "global_load_dwordx4 %6, %8, off offset:96 sc0 sc1\n\t"
                "global_load_dwordx4 %7, %8, off offset:112 sc0 sc1"
                : "=&v"(hw[0]), "=&v"(hw[1]), "=&v"(hw[2]), "=&v"(hw[3]),
                  "=&v"(hw[4]), "=&v"(hw[5]), "=&v"(hw[6]), "=&v"(hw[7])
                : "v"(gp));
            asm volatile("s_waitcnt vmcnt(0)" ::: "memory");
            __builtin_amdgcn_sched_barrier(0);   // rule #18
            u32 err = 0;
#pragma unroll
            for (int i = 0; i < 8; i++) {
                u32x4 v = hw[i];
                err |= (v[0] ^ expect) | (v[1] ^ expect) | (v[2] ^ expect) | (v[3] ^ expect);
            }
            if (__all((int)((err & 0xFFFF0000u) == 0))) break;
            __builtin_amdgcn_s_sleep(1);
        }

        // ---- strip tags, pack pairs, XOR-swizzled LDS write ----
        {
            char* lb = ldsA[t & 1];
#pragma unroll
            for (int q = 0; q < 4; q++) {
                u32x4 a = hw[2 * q], b = hw[2 * q + 1];
                u32x4 pk;
                pk[0] = (a[0] & 0xFFFFu) | (a[1] << 16);
                pk[1] = (a[2] & 0xFFFFu) | (a[3] << 16);
                pk[2] = (b[0] & 0xFFFFu) | (b[1] << 16);
                pk[3] = (b[2] & 0xFFFFu) | (b[3] << 16);
                int off = (((cj * 4 + q) * 16 + crow) * 16) ^ ((cj & 7) << 4);
                *(u32x4*)(lb + off) = pk;
            }
        }
        __syncthreads();   // one barrier/step; dbuf makes a second unnecessary

        // ---- MFMA: A-frags from LDS (compiler-managed lgkmcnt), B resident ----
        f32x4 az = {0.f, 0.f, 0.f, 0.f}, arx = az, ah = az;
        {
            const char* lr = ldsA[t & 1];
#pragma unroll
            for (int kb = 0; kb < 32; kb++) {
                int off = (((kb * 4 + quad) * 16 + l16) * 16) ^ ((kb & 7) << 4);
                f16x8 afr = *(const f16x8*)(lr + off);
                az  = MFMA16(afr, w[kb],      az);
                arx = MFMA16(afr, w[32 + kb], arx);
                ah  = MFMA16(afr, w[64 + kb], ah);
            }
        }

        // ---- gates; fire-and-forget tagged h stores; plain out stores ----
        u32* hwp = hbuf + (long)((t + 1) & 1) * (BB * UU);
        unsigned tagn = (unsigned)(t + 1) << 16;
        float hn[4];
#pragma unroll
        for (int r = 0; r < 4; r++) {
            float z  = 1.f / (1.f + expf(-(xz[r] + az[r] + bhz)));
            float rr = 1.f / (1.f + expf(-(xr[r] + arx[r] + bhr)));
            float cd = tanhf(xh[r] + rr * (ah[r] + bhh));
            hn[r] = z * hold[r] + (1.f - z) * cd;
            hold[r] = hn[r];
        }
        if (t != TT - 1) {
#pragma unroll
            for (int r = 0; r < 4; r++) {
                int b = r0 + quad * 4 + r;
                u32 wv = tagn | (u32)__builtin_bit_cast(unsigned short, (_Float16)hn[r]);
                asm volatile("global_store_dword %0, %1, off sc0 sc1"
                             :: "v"(hwp + (long)b * UU + u0 + l16), "v"(wv) : "memory");
            }
        }
#pragma unroll
        for (int r = 0; r < 4; r++) {
            int b = r0 + quad * 4 + r;
            out[(long)b * TT * UU + (long)t * UU + u0 + l16] = hn[r];
        }
    }
#pragma unroll
    for (int r = 0; r < 4; r++) {
        int b = r0 + quad * 4 + r;
        out[(long)BB * TT * UU + (long)b * UU + u0 + l16] = hold[r];
    }
}

// ---------------- launch ----------------
extern "C" void kernel_launch(void* const* d_in, const int* in_sizes, int n_in,
                              void* d_out, int out_size, void* d_ws, size_t ws_size,
                              hipStream_t stream) {
    const int*   tokens = (const int*)d_in[0];
    const float* hidden = (const float*)d_in[1];
    const float* emb    = (const float*)d_in[2];
    const float* Wx     = (const float*)d_in[3];
    const float* bx     = (const float*)d_in[4];
    const float* Wh     = (const float*)d_in[5];
    const float* bh     = (const float*)d_in[6];
    float* out = (float*)d_out;

    char* ws = (char*)d_ws;
    _Float16* xproj = (_Float16*)(ws);                  // 100663296 B
    _Float16* WhF   = (_Float16*)(ws + 100663296L);     //   6291456 B
    u32*      hbuf  = (u32*)(ws + 106954752L);          //    524288 B (2 slots, tagged)
    if (ws_size < 107479040UL) return;

    prep_whf<<<1536, 256, 0, stream>>>(Wh, WhF);
    prep_h0<<<256, 256, 0, stream>>>(hidden, hbuf);
    proj_kernel<<<dim3(256, 24), 256, 0, stream>>>(tokens, emb, Wx, bx, xproj);
    gru_kernel<<<32, 512, 0, stream>>>(xproj, WhF, hidden, bh, hbuf, out);
}

// Round 5
// 5169.447 us; speedup vs baseline: 1.1346x; 1.1346x over previous
//
#include <hip/hip_runtime.h>
#include <cstdint>

typedef _Float16 f16x8 __attribute__((ext_vector_type(8)));
typedef float    f32x4 __attribute__((ext_vector_type(4)));
typedef unsigned int u32;
typedef u32      u32x4 __attribute__((ext_vector_type(4)));

#define BB 64
#define TT 256
#define EE 512
#define UU 1024
#define NN 3072   // 3*U

#define MFMA16(a, b, c) __builtin_amdgcn_mfma_f32_16x16x32_f16((a), (b), (c), 0, 0, 0)

// ---------------- prep: Wh -> f16 MFMA B-fragment layout ----------------
// WhF[((nt*3+g)*32 + kb)*64 + lane][jj] = f16(Wh[kb*32 + quad*8 + jj][g*1024 + nt*16 + l16])
__global__ __launch_bounds__(256) void prep_whf(const float* __restrict__ Wh,
                                                _Float16* __restrict__ WhF) {
    int tid  = blockIdx.x * 256 + threadIdx.x;
    int col8 = tid % 384;
    int k    = tid / 384;
    int kb = k >> 5, quad = (k >> 3) & 3, jj = k & 7;
    const float* src = Wh + (long)k * NN + col8 * 8;
#pragma unroll
    for (int i = 0; i < 8; i++) {
        int n   = col8 * 8 + i;
        int g   = n >> 10;
        int nl  = n & 1023;
        int jc  = nl >> 4, l16 = nl & 15;
        int lane = quad * 16 + l16;
        WhF[((((jc * 3 + g) * 32 + kb) * 64 + lane) << 3) + jj] = (_Float16)src[i];
    }
}

__global__ __launch_bounds__(256) void prep_h0(const float* __restrict__ h0,
                                               _Float16* __restrict__ hbuf) {
    int i = blockIdx.x * 256 + threadIdx.x;      // 0..65535
    hbuf[i] = (_Float16)h0[i];                   // slot 0; kernel-end flush -> coherent
}

// ---------------- embed + input projection GEMM (f16 MFMA) ----------------
__global__ __launch_bounds__(256) void proj_kernel(
    const int* __restrict__ tokens, const float* __restrict__ emb,
    const float* __restrict__ Wx, const float* __restrict__ bx,
    _Float16* __restrict__ xproj) {
    int tid  = threadIdx.x;
    int wave = tid >> 6, lane = tid & 63, quad = lane >> 4, l16 = lane & 15;
    int bm = blockIdx.x * 64;
    int bn = blockIdx.y * 128;
    int wm = (wave & 1) * 32, wn = (wave >> 1) * 64;

    int row0 = bm + wm + l16;
    const float* a0p = emb + (long)tokens[row0] * EE;
    const float* a1p = emb + (long)tokens[row0 + 16] * EE;

    f32x4 acc[2][4];
#pragma unroll
    for (int mt = 0; mt < 2; mt++)
#pragma unroll
        for (int nt = 0; nt < 4; nt++) { f32x4 z = {0.f, 0.f, 0.f, 0.f}; acc[mt][nt] = z; }

#pragma unroll 2
    for (int k0 = 0; k0 < EE; k0 += 32) {
        int ka = k0 + quad * 8;
        f16x8 afr[2];
        {
            const float4* p = (const float4*)(a0p + ka);
            float4 x0 = p[0], x1 = p[1];
            afr[0][0] = (_Float16)x0.x; afr[0][1] = (_Float16)x0.y;
            afr[0][2] = (_Float16)x0.z; afr[0][3] = (_Float16)x0.w;
            afr[0][4] = (_Float16)x1.x; afr[0][5] = (_Float16)x1.y;
            afr[0][6] = (_Float16)x1.z; afr[0][7] = (_Float16)x1.w;
        }
        {
            const float4* p = (const float4*)(a1p + ka);
            float4 x0 = p[0], x1 = p[1];
            afr[1][0] = (_Float16)x0.x; afr[1][1] = (_Float16)x0.y;
            afr[1][2] = (_Float16)x0.z; afr[1][3] = (_Float16)x0.w;
            afr[1][4] = (_Float16)x1.x; afr[1][5] = (_Float16)x1.y;
            afr[1][6] = (_Float16)x1.z; afr[1][7] = (_Float16)x1.w;
        }
        f16x8 bfr[4];
#pragma unroll
        for (int nt = 0; nt < 4; nt++) {
            const float* bp = Wx + (long)ka * NN + (bn + wn + nt * 16 + l16);
#pragma unroll
            for (int jj = 0; jj < 8; jj++) bfr[nt][jj] = (_Float16)bp[(long)jj * NN];
        }
#pragma unroll
        for (int mt = 0; mt < 2; mt++)
#pragma unroll
            for (int nt = 0; nt < 4; nt++)
                acc[mt][nt] = MFMA16(afr[mt], bfr[nt], acc[mt][nt]);
    }
#pragma unroll
    for (int mt = 0; mt < 2; mt++) {
        int rowbase = bm + wm + mt * 16 + quad * 4;
#pragma unroll
        for (int nt = 0; nt < 4; nt++) {
            int col = bn + wn + nt * 16 + l16;
            float bias = bx[col];
#pragma unroll
            for (int r = 0; r < 4; r++) {
                int i = rowbase + r;
                int b = i >> 8, t = i & 255;
                xproj[((long)t * BB + b) * NN + col] = (_Float16)(acc[mt][nt][r] + bias);
            }
        }
    }
}

// ---------------- persistent GRU recurrence: domains + flag/payload ----------------
// R7: keep R6's proven shape (4 batch-domains x 8 WGs, 512 thr; per-WG h
// payload only 32KB, LDS-shared by 8 waves; 96 weight frags register-
// resident). Replace ONLY the exchange protocol — R6's regression (21us/
// step) was (a) polling by re-loading 64KB payload per retry (coherent-
// fabric congestion collapse) and (b) scalar-granularity h stores (64K
// dword transactions/step). Fix:
//  1. poll on a 16-BYTE flag vector (8 u16/domain, one dwordx4 covers all
//     producers), s_sleep(8) backoff -> 4000x less poll traffic;
//  2. payload untagged f16, read ONCE after flags pass (64B/thread
//     dwordx4), staged to XOR-swizzled LDS;
//  3. producer h stores coalesced via LDS transpose: 256 x 16B dwordx4
//     per WG (8x fewer transactions), then vmcnt(0) + barrier + u16 flag.
// Visibility chain = R3's proven primitives (write-through sc0sc1 ->
// vmcnt ack -> flag; poll -> sc0sc1 payload read). Anti-overwrite: flag=t
// from WG k implies k finished reading h_{t-1}; writers of slot (t+1)&1
// (overwriting h_{t-1}) first wait all flags >= t. No atomics, no fences,
// no XCD-placement assumptions (G16-safe).
__global__ __launch_bounds__(512, 1) void gru_kernel(
    const _Float16* __restrict__ xproj,    // [T][B][3U]
    const _Float16* __restrict__ WhF,      // fragment layout
    const float* __restrict__ hidden,      // [B][U] fp32 h0
    const float* __restrict__ bh,          // [3U]
    _Float16* __restrict__ hbuf,           // [2][B][U] f16 h exchange
    unsigned short* __restrict__ flags,    // [4 domains][8 producers]
    float* __restrict__ out) {             // [B][T][U] ++ [B][U]
    __shared__ char     ldsA[32768];       // 16 x 1024 f16 A-block (swizzled)
    __shared__ _Float16 ldsT[16 * 128];    // 4KB transpose buffer for h stores
    int tid  = threadIdx.x;
    int wave = tid >> 6, lane = tid & 63, quad = lane >> 4, l16 = lane & 15;
    int wg = blockIdx.x;                   // 0..31
    int d  = wg >> 3;                      // domain: batch rows [16d,16d+16)
    int s  = wg & 7;                       // u-slice of 128 cols
    int ntile = s * 8 + wave;              // wave's 16-col u-tile (0..63)
    int u0 = ntile * 16;
    int r0 = d * 16;

    // ---- weights: 96 frags/wave register-resident (64 AGPR + 32 VGPR) ----
    const f16x8* WF = (const f16x8*)WhF + (long)ntile * 96 * 64 + lane;
    f16x8 w[96];                           // w[g*32+kb], g=0:z 1:r 2:cand
#pragma unroll
    for (int i = 0; i < 96; i++) w[i] = WF[(long)i * 64];
#pragma unroll
    for (int i = 0; i < 64; i++) asm volatile("" : "+a"(w[i]));
#pragma unroll
    for (int i = 64; i < 96; i++) asm volatile("" : "+v"(w[i]));

    float bhz = bh[u0 + l16], bhr = bh[UU + u0 + l16], bhh = bh[2 * UU + u0 + l16];

    float hold[4];
#pragma unroll
    for (int r = 0; r < 4; r++)
        hold[r] = hidden[(long)(r0 + quad * 4 + r) * UU + u0 + l16];

    // payload-load mapping: thread -> (row prow, 64B col chunk pcj)
    int prow = tid >> 5;                   // 0..15
    int pcj  = tid & 31;                   // 32 chunks x 64B = 2KB row
    const u32* fvec = (const u32*)(flags + d * 8);   // 16B flag vector

#pragma unroll 1
    for (int t = 0; t < TT; t++) {
        // ---- x loads (plain cached; latency hides under poll) ----
        float xz[4], xr[4], xh[4];
        {
            const _Float16* xp = xproj + (long)t * BB * NN + u0 + l16;
#pragma unroll
            for (int r = 0; r < 4; r++) {
                const _Float16* p = xp + (long)(r0 + quad * 4 + r) * NN;
                xz[r] = (float)p[0]; xr[r] = (float)p[UU]; xh[r] = (float)p[2 * UU];
            }
        }

        // ---- poll the 8 producer flags of this domain (16B, all lanes) ----
        if (t) {
            u32 tt = (u32)t;
            for (;;) {
                u32x4 fv;
                asm volatile("global_load_dwordx4 %0, %1, off sc0 sc1\n\t"
                             "s_waitcnt vmcnt(0)"
                             : "=v"(fv) : "v"(fvec) : "memory");
                bool ok = ((fv[0] & 0xFFFFu) >= tt) & ((fv[0] >> 16) >= tt) &
                          ((fv[1] & 0xFFFFu) >= tt) & ((fv[1] >> 16) >= tt) &
                          ((fv[2] & 0xFFFFu) >= tt) & ((fv[2] >> 16) >= tt) &
                          ((fv[3] & 0xFFFFu) >= tt) & ((fv[3] >> 16) >= tt);
                if (ok) break;
                __builtin_amdgcn_s_sleep(8);
            }
        }

        // ---- payload: 64B/thread coherent read, once; stage to LDS ----
        {
            const _Float16* gp = hbuf + (long)(t & 1) * (BB * UU)
                                      + (long)(r0 + prow) * UU + pcj * 32;
            f16x8 hv0, hv1, hv2, hv3;
            asm volatile(
                "global_load_dwordx4 %0, %4, off sc0 sc1\n\t"
                "global_load_dwordx4 %1, %4, off offset:16 sc0 sc1\n\t"
                "global_load_dwordx4 %2, %4, off offset:32 sc0 sc1\n\t"
                "global_load_dwordx4 %3, %4, off offset:48 sc0 sc1"
                : "=&v"(hv0), "=&v"(hv1), "=&v"(hv2), "=&v"(hv3) : "v"(gp));
            asm volatile("s_waitcnt vmcnt(0)" ::: "memory");
            __builtin_amdgcn_sched_barrier(0);   // rule #18
            char* lb = ldsA + prow * 2048;
            int sw = (prow & 7) << 4;
            *(f16x8*)(lb + (((pcj * 64) + 0)  ^ sw)) = hv0;
            *(f16x8*)(lb + (((pcj * 64) + 16) ^ sw)) = hv1;
            *(f16x8*)(lb + (((pcj * 64) + 32) ^ sw)) = hv2;
            *(f16x8*)(lb + (((pcj * 64) + 48) ^ sw)) = hv3;
        }
        __syncthreads();   // B1: A-block staged

        // ---- MFMA: A from swizzled LDS, B register-resident ----
        f32x4 az = {0.f, 0.f, 0.f, 0.f}, arx = az, ah = az;
        {
            const char* lr = ldsA + l16 * 2048;
            int sw = (l16 & 7) << 4;
#pragma unroll
            for (int kb = 0; kb < 32; kb++) {
                f16x8 afr = *(const f16x8*)(lr + ((kb * 64 + quad * 16) ^ sw));
                az  = MFMA16(afr, w[kb],      az);
                arx = MFMA16(afr, w[32 + kb], arx);
                ah  = MFMA16(afr, w[64 + kb], ah);
            }
        }

        // ---- gates ----
        float hn[4];
#pragma unroll
        for (int r = 0; r < 4; r++) {
            float z  = 1.f / (1.f + expf(-(xz[r] + az[r] + bhz)));
            float rr = 1.f / (1.f + expf(-(xr[r] + arx[r] + bhr)));
            float cd = tanhf(xh[r] + rr * (ah[r] + bhh));
            hn[r] = z * hold[r] + (1.f - z) * cd;
            hold[r] = hn[r];
        }

        // ---- transpose-stage h tile; coalesced coherent stores; flag ----
#pragma unroll
        for (int r = 0; r < 4; r++)
            ldsT[(quad * 4 + r) * 128 + wave * 16 + l16] = (_Float16)hn[r];
        __syncthreads();   // B2: T-tile staged (also: all A-reads done)
        if (t != TT - 1) {
            if (tid < 256) {
                int trow = tid >> 4, tc = tid & 15;
                f16x8 vv = *(const f16x8*)(ldsT + trow * 128 + tc * 8);
                _Float16* dst = hbuf + (long)((t + 1) & 1) * (BB * UU)
                                     + (long)(r0 + trow) * UU + s * 128 + tc * 8;
                asm volatile("global_store_dwordx4 %0, %1, off sc0 sc1"
                             :: "v"(dst), "v"(vv) : "memory");
                asm volatile("s_waitcnt vmcnt(0)" ::: "memory");
            }
            __syncthreads();   // B3: every thread's h stores acked at LLC
            if (tid == 0) {
                unsigned short* fdst = flags + d * 8 + s;
                asm volatile("global_store_short %0, %1, off sc0 sc1"
                             :: "v"(fdst), "v"((u32)(t + 1)) : "memory");
            }
        }

        // ---- fp32 outputs (plain; off the critical path) ----
#pragma unroll
        for (int r = 0; r < 4; r++) {
            int b = r0 + quad * 4 + r;
            out[(long)b * TT * UU + (long)t * UU + u0 + l16] = hn[r];
        }
    }
#pragma unroll
    for (int r = 0; r < 4; r++) {
        int b = r0 + quad * 4 + r;
        out[(long)BB * TT * UU + (long)b * UU + u0 + l16] = hold[r];
    }
}

// ---------------- launch ----------------
extern "C" void kernel_launch(void* const* d_in, const int* in_sizes, int n_in,
                              void* d_out, int out_size, void* d_ws, size_t ws_size,
                              hipStream_t stream) {
    const int*   tokens = (const int*)d_in[0];
    const float* hidden = (const float*)d_in[1];
    const float* emb    = (const float*)d_in[2];
    const float* Wx     = (const float*)d_in[3];
    const float* bx     = (const float*)d_in[4];
    const float* Wh     = (const float*)d_in[5];
    const float* bh     = (const float*)d_in[6];
    float* out = (float*)d_out;

    char* ws = (char*)d_ws;
    _Float16*       xproj = (_Float16*)(ws);                  // 100663296 B
    _Float16*       WhF   = (_Float16*)(ws + 100663296L);     //   6291456 B
    _Float16*       hbuf  = (_Float16*)(ws + 106954752L);     //    262144 B
    unsigned short* flags = (unsigned short*)(ws + 107216896L); //      64 B
    if (ws_size < 107217152UL) return;

    hipMemsetAsync(flags, 0, 64, stream);
    prep_whf<<<1536, 256, 0, stream>>>(Wh, WhF);
    prep_h0<<<256, 256, 0, stream>>>(hidden, hbuf);
    proj_kernel<<<dim3(256, 24), 256, 0, stream>>>(tokens, emb, Wx, bx, xproj);
    gru_kernel<<<32, 512, 0, stream>>>(xproj, WhF, hidden, bh, hbuf, flags, out);
}

// Round 6
// 5060.521 us; speedup vs baseline: 1.1590x; 1.0215x over previous
//
#include <hip/hip_runtime.h>
#include <cstdint>

typedef _Float16 f16x8 __attribute__((ext_vector_type(8)));
typedef float    f32x4 __attribute__((ext_vector_type(4)));
typedef unsigned int u32;
typedef u32      u32x4 __attribute__((ext_vector_type(4)));

#define BB 64
#define TT 256
#define EE 512
#define UU 1024
#define NN 3072   // 3*U

#define MFMA16(a, b, c) __builtin_amdgcn_mfma_f32_16x16x32_f16((a), (b), (c), 0, 0, 0)

// ---------------- prep: Wh -> f16 MFMA B-fragment layout ----------------
__global__ __launch_bounds__(256) void prep_whf(const float* __restrict__ Wh,
                                                _Float16* __restrict__ WhF) {
    int tid  = blockIdx.x * 256 + threadIdx.x;
    int col8 = tid % 384;
    int k    = tid / 384;
    int kb = k >> 5, quad = (k >> 3) & 3, jj = k & 7;
    const float* src = Wh + (long)k * NN + col8 * 8;
#pragma unroll
    for (int i = 0; i < 8; i++) {
        int n   = col8 * 8 + i;
        int g   = n >> 10;
        int nl  = n & 1023;
        int jc  = nl >> 4, l16 = nl & 15;
        int lane = quad * 16 + l16;
        WhF[((((jc * 3 + g) * 32 + kb) * 64 + lane) << 3) + jj] = (_Float16)src[i];
    }
}

__global__ __launch_bounds__(256) void prep_h0(const float* __restrict__ h0,
                                               _Float16* __restrict__ hbuf) {
    int i = blockIdx.x * 256 + threadIdx.x;      // 0..65535
    hbuf[i] = (_Float16)h0[i];                   // slot 0; kernel-end flush -> coherent
}

// ---------------- embed + input projection GEMM (f16 MFMA) ----------------
__global__ __launch_bounds__(256) void proj_kernel(
    const int* __restrict__ tokens, const float* __restrict__ emb,
    const float* __restrict__ Wx, const float* __restrict__ bx,
    _Float16* __restrict__ xproj) {
    int tid  = threadIdx.x;
    int wave = tid >> 6, lane = tid & 63, quad = lane >> 4, l16 = lane & 15;
    int bm = blockIdx.x * 64;
    int bn = blockIdx.y * 128;
    int wm = (wave & 1) * 32, wn = (wave >> 1) * 64;

    int row0 = bm + wm + l16;
    const float* a0p = emb + (long)tokens[row0] * EE;
    const float* a1p = emb + (long)tokens[row0 + 16] * EE;

    f32x4 acc[2][4];
#pragma unroll
    for (int mt = 0; mt < 2; mt++)
#pragma unroll
        for (int nt = 0; nt < 4; nt++) { f32x4 z = {0.f, 0.f, 0.f, 0.f}; acc[mt][nt] = z; }

#pragma unroll 2
    for (int k0 = 0; k0 < EE; k0 += 32) {
        int ka = k0 + quad * 8;
        f16x8 afr[2];
        {
            const float4* p = (const float4*)(a0p + ka);
            float4 x0 = p[0], x1 = p[1];
            afr[0][0] = (_Float16)x0.x; afr[0][1] = (_Float16)x0.y;
            afr[0][2] = (_Float16)x0.z; afr[0][3] = (_Float16)x0.w;
            afr[0][4] = (_Float16)x1.x; afr[0][5] = (_Float16)x1.y;
            afr[0][6] = (_Float16)x1.z; afr[0][7] = (_Float16)x1.w;
        }
        {
            const float4* p = (const float4*)(a1p + ka);
            float4 x0 = p[0], x1 = p[1];
            afr[1][0] = (_Float16)x0.x; afr[1][1] = (_Float16)x0.y;
            afr[1][2] = (_Float16)x0.z; afr[1][3] = (_Float16)x0.w;
            afr[1][4] = (_Float16)x1.x; afr[1][5] = (_Float16)x1.y;
            afr[1][6] = (_Float16)x1.z; afr[1][7] = (_Float16)x1.w;
        }
        f16x8 bfr[4];
#pragma unroll
        for (int nt = 0; nt < 4; nt++) {
            const float* bp = Wx + (long)ka * NN + (bn + wn + nt * 16 + l16);
#pragma unroll
            for (int jj = 0; jj < 8; jj++) bfr[nt][jj] = (_Float16)bp[(long)jj * NN];
        }
#pragma unroll
        for (int mt = 0; mt < 2; mt++)
#pragma unroll
            for (int nt = 0; nt < 4; nt++)
                acc[mt][nt] = MFMA16(afr[mt], bfr[nt], acc[mt][nt]);
    }
#pragma unroll
    for (int mt = 0; mt < 2; mt++) {
        int rowbase = bm + wm + mt * 16 + quad * 4;
#pragma unroll
        for (int nt = 0; nt < 4; nt++) {
            int col = bn + wn + nt * 16 + l16;
            float bias = bx[col];
#pragma unroll
            for (int r = 0; r < 4; r++) {
                int i = rowbase + r;
                int b = i >> 8, t = i & 255;
                xproj[((long)t * BB + b) * NN + col] = (_Float16)(acc[mt][nt][r] + bias);
            }
        }
    }
}

// ---------------- persistent GRU recurrence: domains + flag/payload ----------------
// R8 = R7 with ONE change that matters: the poll is executed by tid==0
// ALONE. R7 had all 512 threads issue sc0sc1 loads of the SAME 16-B flag
// line -> ~16K same-line LLC transactions per retry round chip-wide,
// serviced serially by one LLC bank (~7us/round) — THE dominant cost of
// R3/R6/R7 alike (coherent loads never coalesce). Now: 32 transactions/
// round (one per WG), broadcast by the existing __syncthreads.
// Cost model (R2-R8): per-step = serial RTs (~0.3-0.5us each, fine)
//                     + same-line coherent transactions (the killer).
//  - payload read once per WG (spread addresses -> parallel LLC banks)
//  - producer h stores coalesced 16B via LDS transpose, vmcnt ack, u16 flag
//  - 4 batch-domains x 8 WGs; 96 weight frags/wave register-resident
//  - anti-overwrite induction + t=0 kernel-boundary visibility: as R7
//  - ldsT stride padded 128->136 (clears the 1.5e7 bank-conflict cycles)
__global__ __launch_bounds__(512, 1) void gru_kernel(
    const _Float16* __restrict__ xproj,    // [T][B][3U]
    const _Float16* __restrict__ WhF,      // fragment layout
    const float* __restrict__ hidden,      // [B][U] fp32 h0
    const float* __restrict__ bh,          // [3U]
    _Float16* __restrict__ hbuf,           // [2][B][U] f16 h exchange
    unsigned short* __restrict__ flags,    // [4 domains][8 producers]
    float* __restrict__ out) {             // [B][T][U] ++ [B][U]
    __shared__ char     ldsA[32768];       // 16 x 1024 f16 A-block (swizzled)
    __shared__ _Float16 ldsT[16 * 136];    // padded transpose buffer
    int tid  = threadIdx.x;
    int wave = tid >> 6, lane = tid & 63, quad = lane >> 4, l16 = lane & 15;
    int wg = blockIdx.x;                   // 0..31
    int d  = wg >> 3;                      // domain: batch rows [16d,16d+16)
    int s  = wg & 7;                       // u-slice of 128 cols
    int ntile = s * 8 + wave;              // wave's 16-col u-tile (0..63)
    int u0 = ntile * 16;
    int r0 = d * 16;

    // ---- weights: 96 frags/wave register-resident (64 AGPR + 32 VGPR) ----
    const f16x8* WF = (const f16x8*)WhF + (long)ntile * 96 * 64 + lane;
    f16x8 w[96];                           // w[g*32+kb], g=0:z 1:r 2:cand
#pragma unroll
    for (int i = 0; i < 96; i++) w[i] = WF[(long)i * 64];
#pragma unroll
    for (int i = 0; i < 64; i++) asm volatile("" : "+a"(w[i]));
#pragma unroll
    for (int i = 64; i < 96; i++) asm volatile("" : "+v"(w[i]));

    float bhz = bh[u0 + l16], bhr = bh[UU + u0 + l16], bhh = bh[2 * UU + u0 + l16];

    float hold[4];
#pragma unroll
    for (int r = 0; r < 4; r++)
        hold[r] = hidden[(long)(r0 + quad * 4 + r) * UU + u0 + l16];

    // payload-load mapping: thread -> (row prow, 64B col chunk pcj)
    int prow = tid >> 5;                   // 0..15
    int pcj  = tid & 31;                   // 32 chunks x 64B = 2KB row
    const u32* fvec = (const u32*)(flags + d * 8);   // 16B flag vector

#pragma unroll 1
    for (int t = 0; t < TT; t++) {
        // ---- x loads (plain cached; latency hides under poll/payload) ----
        float xz[4], xr[4], xh[4];
        {
            const _Float16* xp = xproj + (long)t * BB * NN + u0 + l16;
#pragma unroll
            for (int r = 0; r < 4; r++) {
                const _Float16* p = xp + (long)(r0 + quad * 4 + r) * NN;
                xz[r] = (float)p[0]; xr[r] = (float)p[UU]; xh[r] = (float)p[2 * UU];
            }
        }

        // ---- poll: tid==0 ONLY (32 chip-wide transactions/round) ----
        if (t) {
            if (tid == 0) {
                u32 tt = (u32)t;
                for (;;) {
                    u32x4 fv;
                    asm volatile("global_load_dwordx4 %0, %1, off sc0 sc1\n\t"
                                 "s_waitcnt vmcnt(0)"
                                 : "=v"(fv) : "v"(fvec) : "memory");
                    bool ok = ((fv[0] & 0xFFFFu) >= tt) & ((fv[0] >> 16) >= tt) &
                              ((fv[1] & 0xFFFFu) >= tt) & ((fv[1] >> 16) >= tt) &
                              ((fv[2] & 0xFFFFu) >= tt) & ((fv[2] >> 16) >= tt) &
                              ((fv[3] & 0xFFFFu) >= tt) & ((fv[3] >> 16) >= tt);
                    if (ok) break;
                    __builtin_amdgcn_s_sleep(1);
                }
            }
            __syncthreads();   // broadcast "domain ready" to all 8 waves
        }

        // ---- payload: 64B/thread coherent read, once; stage to LDS ----
        {
            const _Float16* gp = hbuf + (long)(t & 1) * (BB * UU)
                                      + (long)(r0 + prow) * UU + pcj * 32;
            f16x8 hv0, hv1, hv2, hv3;
            asm volatile(
                "global_load_dwordx4 %0, %4, off sc0 sc1\n\t"
                "global_load_dwordx4 %1, %4, off offset:16 sc0 sc1\n\t"
                "global_load_dwordx4 %2, %4, off offset:32 sc0 sc1\n\t"
                "global_load_dwordx4 %3, %4, off offset:48 sc0 sc1"
                : "=&v"(hv0), "=&v"(hv1), "=&v"(hv2), "=&v"(hv3) : "v"(gp));
            asm volatile("s_waitcnt vmcnt(0)" ::: "memory");
            __builtin_amdgcn_sched_barrier(0);   // rule #18
            char* lb = ldsA + prow * 2048;
            int sw = (prow & 7) << 4;
            *(f16x8*)(lb + (((pcj * 64) + 0)  ^ sw)) = hv0;
            *(f16x8*)(lb + (((pcj * 64) + 16) ^ sw)) = hv1;
            *(f16x8*)(lb + (((pcj * 64) + 32) ^ sw)) = hv2;
            *(f16x8*)(lb + (((pcj * 64) + 48) ^ sw)) = hv3;
        }
        __syncthreads();   // B1: A-block staged

        // ---- MFMA: A from swizzled LDS, B register-resident ----
        f32x4 az = {0.f, 0.f, 0.f, 0.f}, arx = az, ah = az;
        {
            const char* lr = ldsA + l16 * 2048;
            int sw = (l16 & 7) << 4;
#pragma unroll
            for (int kb = 0; kb < 32; kb++) {
                f16x8 afr = *(const f16x8*)(lr + ((kb * 64 + quad * 16) ^ sw));
                az  = MFMA16(afr, w[kb],      az);
                arx = MFMA16(afr, w[32 + kb], arx);
                ah  = MFMA16(afr, w[64 + kb], ah);
            }
        }

        // ---- gates ----
        float hn[4];
#pragma unroll
        for (int r = 0; r < 4; r++) {
            float z  = 1.f / (1.f + expf(-(xz[r] + az[r] + bhz)));
            float rr = 1.f / (1.f + expf(-(xr[r] + arx[r] + bhr)));
            float cd = tanhf(xh[r] + rr * (ah[r] + bhh));
            hn[r] = z * hold[r] + (1.f - z) * cd;
            hold[r] = hn[r];
        }

        // ---- transpose-stage h tile; coalesced coherent stores; flag ----
#pragma unroll
        for (int r = 0; r < 4; r++)
            ldsT[(quad * 4 + r) * 136 + wave * 16 + l16] = (_Float16)hn[r];
        __syncthreads();   // B2: T-tile staged (also: all A-reads done)
        if (t != TT - 1) {
            if (tid < 256) {
                int trow = tid >> 4, tc = tid & 15;
                f16x8 vv = *(const f16x8*)(ldsT + trow * 136 + tc * 8);
                _Float16* dst = hbuf + (long)((t + 1) & 1) * (BB * UU)
                                     + (long)(r0 + trow) * UU + s * 128 + tc * 8;
                asm volatile("global_store_dwordx4 %0, %1, off sc0 sc1"
                             :: "v"(dst), "v"(vv) : "memory");
                asm volatile("s_waitcnt vmcnt(0)" ::: "memory");
            }
            __syncthreads();   // B3: every thread's h stores acked
            if (tid == 0) {
                unsigned short* fdst = flags + d * 8 + s;
                asm volatile("global_store_short %0, %1, off sc0 sc1"
                             :: "v"(fdst), "v"((u32)(t + 1)) : "memory");
            }
        }

        // ---- fp32 outputs (plain; off the critical path) ----
#pragma unroll
        for (int r = 0; r < 4; r++) {
            int b = r0 + quad * 4 + r;
            out[(long)b * TT * UU + (long)t * UU + u0 + l16] = hn[r];
        }
    }
#pragma unroll
    for (int r = 0; r < 4; r++) {
        int b = r0 + quad * 4 + r;
        out[(long)BB * TT * UU + (long)b * UU + u0 + l16] = hold[r];
    }
}

// ---------------- launch ----------------
extern "C" void kernel_launch(void* const* d_in, const int* in_sizes, int n_in,
                              void* d_out, int out_size, void* d_ws, size_t ws_size,
                              hipStream_t stream) {
    const int*   tokens = (const int*)d_in[0];
    const float* hidden = (const float*)d_in[1];
    const float* emb    = (const float*)d_in[2];
    const float* Wx     = (const float*)d_in[3];
    const float* bx     = (const float*)d_in[4];
    const float* Wh     = (const float*)d_in[5];
    const float* bh     = (const float*)d_in[6];
    float* out = (float*)d_out;

    char* ws = (char*)d_ws;
    _Float16*       xproj = (_Float16*)(ws);                  // 100663296 B
    _Float16*       WhF   = (_Float16*)(ws + 100663296L);     //   6291456 B
    _Float16*       hbuf  = (_Float16*)(ws + 106954752L);     //    262144 B
    unsigned short* flags = (unsigned short*)(ws + 107216896L); //      64 B
    if (ws_size < 107217152UL) return;

    hipMemsetAsync(flags, 0, 64, stream);
    prep_whf<<<1536, 256, 0, stream>>>(Wh, WhF);
    prep_h0<<<256, 256, 0, stream>>>(hidden, hbuf);
    proj_kernel<<<dim3(256, 24), 256, 0, stream>>>(tokens, emb, Wx, bx, xproj);
    gru_kernel<<<32, 512, 0, stream>>>(xproj, WhF, hidden, bh, hbuf, flags, out);
}

// Round 7
// 2579.787 us; speedup vs baseline: 2.2736x; 1.9616x over previous
//
#include <hip/hip_runtime.h>
#include <cstdint>

typedef _Float16 f16x8 __attribute__((ext_vector_type(8)));
typedef float    f32x4 __attribute__((ext_vector_type(4)));
typedef unsigned int u32;

#define BB 64
#define TT 256
#define EE 512
#define UU 1024
#define NN 3072   // 3*U

// ---------------- prep: Wh -> f16 MFMA B-fragment layout ----------------
// WhF[((j*3+g)*32 + kb)*64 + lane][jj] = f16(Wh[kb*32 + quad*8 + jj][g*1024 + j*16 + l16])
__global__ __launch_bounds__(256) void prep_whf(const float* __restrict__ Wh,
                                                _Float16* __restrict__ WhF) {
    int tid  = blockIdx.x * 256 + threadIdx.x;   // 0..393215
    int col8 = tid % 384;                        // group of 8 consecutive columns
    int k    = tid / 384;                        // 0..1023
    int kb = k >> 5, quad = (k >> 3) & 3, jj = k & 7;
    const float* src = Wh + (long)k * NN + col8 * 8;
#pragma unroll
    for (int i = 0; i < 8; i++) {
        int n   = col8 * 8 + i;
        int g   = n >> 10;
        int nl  = n & 1023;
        int j   = nl >> 4, l16 = nl & 15;
        int lane = quad * 16 + l16;
        WhF[((((j * 3 + g) * 32 + kb) * 64 + lane) << 3) + jj] = (_Float16)src[i];
    }
}

__global__ __launch_bounds__(256) void prep_h0(const float* __restrict__ h0,
                                               _Float16* __restrict__ hbuf) {
    int i = blockIdx.x * 256 + threadIdx.x;      // 0..65535
    hbuf[i] = (_Float16)h0[i];
}

// ---------------- embed + input projection GEMM (f16 MFMA) ----------------
__global__ __launch_bounds__(256) void proj_kernel(
    const int* __restrict__ tokens, const float* __restrict__ emb,
    const float* __restrict__ Wx, const float* __restrict__ bx,
    _Float16* __restrict__ xproj) {
    int tid  = threadIdx.x;
    int wave = tid >> 6, lane = tid & 63, quad = lane >> 4, l16 = lane & 15;
    int bm = blockIdx.x * 64;           // M offset (i = b*T+t)
    int bn = blockIdx.y * 128;          // N offset
    int wm = (wave & 1) * 32, wn = (wave >> 1) * 64;

    int row0 = bm + wm + l16;
    const float* a0p = emb + (long)tokens[row0] * EE;
    const float* a1p = emb + (long)tokens[row0 + 16] * EE;

    f32x4 acc[2][4];
#pragma unroll
    for (int mt = 0; mt < 2; mt++)
#pragma unroll
        for (int nt = 0; nt < 4; nt++) { f32x4 z = {0.f, 0.f, 0.f, 0.f}; acc[mt][nt] = z; }

#pragma unroll 2
    for (int k0 = 0; k0 < EE; k0 += 32) {
        int ka = k0 + quad * 8;
        f16x8 afr[2];
        {
            const float4* p = (const float4*)(a0p + ka);
            float4 x0 = p[0], x1 = p[1];
            afr[0][0] = (_Float16)x0.x; afr[0][1] = (_Float16)x0.y;
            afr[0][2] = (_Float16)x0.z; afr[0][3] = (_Float16)x0.w;
            afr[0][4] = (_Float16)x1.x; afr[0][5] = (_Float16)x1.y;
            afr[0][6] = (_Float16)x1.z; afr[0][7] = (_Float16)x1.w;
        }
        {
            const float4* p = (const float4*)(a1p + ka);
            float4 x0 = p[0], x1 = p[1];
            afr[1][0] = (_Float16)x0.x; afr[1][1] = (_Float16)x0.y;
            afr[1][2] = (_Float16)x0.z; afr[1][3] = (_Float16)x0.w;
            afr[1][4] = (_Float16)x1.x; afr[1][5] = (_Float16)x1.y;
            afr[1][6] = (_Float16)x1.z; afr[1][7] = (_Float16)x1.w;
        }
        f16x8 bfr[4];
#pragma unroll
        for (int nt = 0; nt < 4; nt++) {
            const float* bp = Wx + (long)ka * NN + (bn + wn + nt * 16 + l16);
#pragma unroll
            for (int jj = 0; jj < 8; jj++) bfr[nt][jj] = (_Float16)bp[(long)jj * NN];
        }
#pragma unroll
        for (int mt = 0; mt < 2; mt++)
#pragma unroll
            for (int nt = 0; nt < 4; nt++)
                acc[mt][nt] = __builtin_amdgcn_mfma_f32_16x16x32_f16(afr[mt], bfr[nt], acc[mt][nt], 0, 0, 0);
    }
#pragma unroll
    for (int mt = 0; mt < 2; mt++) {
        int rowbase = bm + wm + mt * 16 + quad * 4;
#pragma unroll
        for (int nt = 0; nt < 4; nt++) {
            int col = bn + wn + nt * 16 + l16;
            float bias = bx[col];
#pragma unroll
            for (int r = 0; r < 4; r++) {
                int i = rowbase + r;
                int b = i >> 8, t = i & 255;          // T = 256
                xproj[((long)t * BB + b) * NN + col] = (_Float16)(acc[mt][nt][r] + bias);
            }
        }
    }
}

// ---------------- persistent GRU recurrence ----------------
// R9 = the R2 skeleton (best measured: 9.6us/step; 64 WG x 256 thr, weights
// register-resident, DIRECT plain cached h loads feeding MFMA, ONE sync
// point/step) with its two serial sync costs surgically removed:
//  1. h stores are write-through sc0sc1 shorts (R3-proven: vmcnt drain =>
//     at LLC). The pre-sync __syncthreads drains each wave's vmcnt, so the
//     counter RMW is RELAXED -> NO buffer_wbl2 (release walk) in the chain.
//     The read-side ACQUIRE fence (buffer_inv) stays: readers use plain
//     cached loads and the h slot was in L2 from 2 steps ago (R2-proven).
//  2. counter tree: 8 counters 64B apart (8 parallel LLC bank chains of 8
//     RMWs instead of one chain of 64). Spin reads all 8 via one pipelined
//     8-load asm block (~1 round trip per retry, tid==0 only).
// Sum-semantics safety: a WG's add #(t+1) occurs only after it passed
// wait(8t) on ALL counters => at the first instant any counter reaches 8t,
// every WG has completed exactly t adds (wait-between-adds induction).
// Evidence base: R2 9.6us/step vs R3 11.5 vs R6-8 18-21 -> the 64x256
// direct-load structure dominates; protocol families only perturb +-10%.
__global__ __launch_bounds__(256, 1) void gru_kernel(
    const _Float16* __restrict__ xproj,   // [T][B][3U]
    const _Float16* __restrict__ WhF,     // fragment layout
    const float* __restrict__ hidden,     // [B][U] fp32 h0
    const float* __restrict__ bh,         // [3U]
    _Float16* __restrict__ hbuf,          // [2][B][U]
    u32* cnt,                             // 8 counters, 64B apart
    float* __restrict__ out) {            // [B][T][U] ++ [B][U]
    int tid  = threadIdx.x;
    int wave = tid >> 6, lane = tid & 63, quad = lane >> 4, l16 = lane & 15;
    int j  = blockIdx.x;
    int u  = j * 16 + l16;
    int b0 = wave * 16;

    float bhz = bh[u], bhr = bh[UU + u], bhh = bh[2 * UU + u];

    float hold[4];
#pragma unroll
    for (int r = 0; r < 4; r++) hold[r] = hidden[(long)(b0 + quad * 4 + r) * UU + u];

    // ---- load the whole per-WG weight slice into registers, ONCE ----
    // (R2-proven pin: 60 frags -> AGPR, 36 -> VGPR; opaque asm producer)
    const f16x8* WF = (const f16x8*)WhF + (long)j * 3 * 32 * 64 + lane;
    f16x8 w[96];                      // w[g*32+kb]
#pragma unroll
    for (int i = 0; i < 96; i++) w[i] = WF[(long)i * 64];
#pragma unroll
    for (int i = 0; i < 60; i++) asm volatile("" : "+a"(w[i]));
#pragma unroll
    for (int i = 60; i < 96; i++) asm volatile("" : "+v"(w[i]));

#pragma unroll 1
    for (int t = 0; t < TT; t++) {
        const _Float16* xp = xproj + (long)t * BB * NN;
        float xzv[4], xrv[4], xhv[4];
#pragma unroll
        for (int r = 0; r < 4; r++) {
            const _Float16* p = xp + (long)(b0 + quad * 4 + r) * NN + u;
            xzv[r] = (float)p[0]; xrv[r] = (float)p[UU]; xhv[r] = (float)p[2 * UU];
        }

        // ---- h loads: PLAIN CACHED, wide and deep, direct into MFMA ----
        const _Float16* h = hbuf + (long)(t & 1) * BB * UU + (long)(b0 + l16) * UU + quad * 8;
        f32x4 az = {0.f, 0.f, 0.f, 0.f}, ar = az, ah = az;
#pragma unroll
        for (int kb = 0; kb < 32; kb++) {
            f16x8 afr = *(const f16x8*)(h + kb * 32);
            az = __builtin_amdgcn_mfma_f32_16x16x32_f16(afr, w[kb],      az, 0, 0, 0);
            ar = __builtin_amdgcn_mfma_f32_16x16x32_f16(afr, w[32 + kb], ar, 0, 0, 0);
            ah = __builtin_amdgcn_mfma_f32_16x16x32_f16(afr, w[64 + kb], ah, 0, 0, 0);
        }

        // ---- gates; write-through h stores (sc0sc1); plain out stores ----
        _Float16* hw = hbuf + (long)((t + 1) & 1) * BB * UU;
#pragma unroll
        for (int r = 0; r < 4; r++) {
            int b = b0 + quad * 4 + r;
            float z  = 1.f / (1.f + expf(-(xzv[r] + az[r] + bhz)));
            float rr = 1.f / (1.f + expf(-(xrv[r] + ar[r] + bhr)));
            float cd = tanhf(xhv[r] + rr * (ah[r] + bhh));
            float hn = z * hold[r] + (1.f - z) * cd;
            hold[r] = hn;
            out[(long)b * TT * UU + (long)t * UU + u] = hn;
            u32 hv = (u32)__builtin_bit_cast(unsigned short, (_Float16)hn);
            asm volatile("global_store_short %0, %1, off sc0 sc1"
                         :: "v"(hw + (long)b * UU + u), "v"(hv) : "memory");
        }

        if (t != TT - 1) {
            __syncthreads();   // drains each wave's vmcnt -> h at LLC
            if (tid == 0) {
                // RELAXED add (no wbl2): store visibility already ensured
                __hip_atomic_fetch_add(cnt + (j >> 3) * 16, 1u,
                                       __ATOMIC_RELAXED, __HIP_MEMORY_SCOPE_AGENT);
                u32 tgt = 8u * (u32)(t + 1);
                for (;;) {
                    u32 c0, c1, c2, c3, c4, c5, c6, c7;
                    asm volatile(
                        "global_load_dword %0, %8, off sc0 sc1\n\t"
                        "global_load_dword %1, %8, off offset:64 sc0 sc1\n\t"
                        "global_load_dword %2, %8, off offset:128 sc0 sc1\n\t"
                        "global_load_dword %3, %8, off offset:192 sc0 sc1\n\t"
                        "global_load_dword %4, %8, off offset:256 sc0 sc1\n\t"
                        "global_load_dword %5, %8, off offset:320 sc0 sc1\n\t"
                        "global_load_dword %6, %8, off offset:384 sc0 sc1\n\t"
                        "global_load_dword %7, %8, off offset:448 sc0 sc1\n\t"
                        "s_waitcnt vmcnt(0)"
                        : "=&v"(c0), "=&v"(c1), "=&v"(c2), "=&v"(c3),
                          "=&v"(c4), "=&v"(c5), "=&v"(c6), "=&v"(c7)
                        : "v"(cnt) : "memory");
                    if (c0 >= tgt && c1 >= tgt && c2 >= tgt && c3 >= tgt &&
                        c4 >= tgt && c5 >= tgt && c6 >= tgt && c7 >= tgt) break;
                    __builtin_amdgcn_s_sleep(1);
                }
                __builtin_amdgcn_fence(__ATOMIC_ACQUIRE, "agent");  // inv: cached h reads safe
            }
            __syncthreads();
        }
    }
#pragma unroll
    for (int r = 0; r < 4; r++) {
        int b = b0 + quad * 4 + r;
        out[(long)BB * TT * UU + (long)b * UU + u] = hold[r];
    }
}

// ---------------- launch ----------------
extern "C" void kernel_launch(void* const* d_in, const int* in_sizes, int n_in,
                              void* d_out, int out_size, void* d_ws, size_t ws_size,
                              hipStream_t stream) {
    const int*   tokens = (const int*)d_in[0];
    const float* hidden = (const float*)d_in[1];
    const float* emb    = (const float*)d_in[2];
    const float* Wx     = (const float*)d_in[3];
    const float* bx     = (const float*)d_in[4];
    const float* Wh     = (const float*)d_in[5];
    const float* bh     = (const float*)d_in[6];
    float* out = (float*)d_out;

    char* ws = (char*)d_ws;
    _Float16* xproj = (_Float16*)(ws);                  // 100663296 B
    _Float16* WhF   = (_Float16*)(ws + 100663296L);     //   6291456 B
    _Float16* hbuf  = (_Float16*)(ws + 106954752L);     //    262144 B
    u32*      cnt   = (u32*)(ws + 107216896L);          //     512 B (8 ctrs, 64B apart)
    if (ws_size < 107217408UL) return;

    hipMemsetAsync(cnt, 0, 512, stream);
    prep_whf<<<1536, 256, 0, stream>>>(Wh, WhF);
    prep_h0<<<256, 256, 0, stream>>>(hidden, hbuf);
    proj_kernel<<<dim3(256, 24), 256, 0, stream>>>(tokens, emb, Wx, bx, xproj);
    gru_kernel<<<64, 256, 0, stream>>>(xproj, WhF, hidden, bh, hbuf, cnt, out);
}

// Round 8
// 2487.200 us; speedup vs baseline: 2.3582x; 1.0372x over previous
//
#include <hip/hip_runtime.h>
#include <cstdint>

typedef _Float16 f16x8 __attribute__((ext_vector_type(8)));
typedef float    f32x4 __attribute__((ext_vector_type(4)));
typedef unsigned int u32;

#define BB 64
#define TT 256
#define EE 512
#define UU 1024
#define NN 3072   // 3*U

#define MFMA16(a, b, c) __builtin_amdgcn_mfma_f32_16x16x32_f16((a), (b), (c), 0, 0, 0)

// ---------------- prep: Wh -> f16 MFMA B-fragment layout ----------------
// WhF[((j*3+g)*32 + kb)*64 + lane][jj] = f16(Wh[kb*32 + quad*8 + jj][g*1024 + j*16 + l16])
__global__ __launch_bounds__(256) void prep_whf(const float* __restrict__ Wh,
                                                _Float16* __restrict__ WhF) {
    int tid  = blockIdx.x * 256 + threadIdx.x;   // 0..393215
    int col8 = tid % 384;                        // group of 8 consecutive columns
    int k    = tid / 384;                        // 0..1023
    int kb = k >> 5, quad = (k >> 3) & 3, jj = k & 7;
    const float* src = Wh + (long)k * NN + col8 * 8;
#pragma unroll
    for (int i = 0; i < 8; i++) {
        int n   = col8 * 8 + i;
        int g   = n >> 10;
        int nl  = n & 1023;
        int j   = nl >> 4, l16 = nl & 15;
        int lane = quad * 16 + l16;
        WhF[((((j * 3 + g) * 32 + kb) * 64 + lane) << 3) + jj] = (_Float16)src[i];
    }
}

__global__ __launch_bounds__(256) void prep_h0(const float* __restrict__ h0,
                                               _Float16* __restrict__ hbuf) {
    int i = blockIdx.x * 256 + threadIdx.x;      // 0..65535
    hbuf[i] = (_Float16)h0[i];   // kernel-end writeback -> visible to LLC-bypass reads
}

// ---------------- embed + input projection GEMM (f16 MFMA) ----------------
__global__ __launch_bounds__(256) void proj_kernel(
    const int* __restrict__ tokens, const float* __restrict__ emb,
    const float* __restrict__ Wx, const float* __restrict__ bx,
    _Float16* __restrict__ xproj) {
    int tid  = threadIdx.x;
    int wave = tid >> 6, lane = tid & 63, quad = lane >> 4, l16 = lane & 15;
    int bm = blockIdx.x * 64;           // M offset (i = b*T+t)
    int bn = blockIdx.y * 128;          // N offset
    int wm = (wave & 1) * 32, wn = (wave >> 1) * 64;

    int row0 = bm + wm + l16;
    const float* a0p = emb + (long)tokens[row0] * EE;
    const float* a1p = emb + (long)tokens[row0 + 16] * EE;

    f32x4 acc[2][4];
#pragma unroll
    for (int mt = 0; mt < 2; mt++)
#pragma unroll
        for (int nt = 0; nt < 4; nt++) { f32x4 z = {0.f, 0.f, 0.f, 0.f}; acc[mt][nt] = z; }

#pragma unroll 2
    for (int k0 = 0; k0 < EE; k0 += 32) {
        int ka = k0 + quad * 8;
        f16x8 afr[2];
        {
            const float4* p = (const float4*)(a0p + ka);
            float4 x0 = p[0], x1 = p[1];
            afr[0][0] = (_Float16)x0.x; afr[0][1] = (_Float16)x0.y;
            afr[0][2] = (_Float16)x0.z; afr[0][3] = (_Float16)x0.w;
            afr[0][4] = (_Float16)x1.x; afr[0][5] = (_Float16)x1.y;
            afr[0][6] = (_Float16)x1.z; afr[0][7] = (_Float16)x1.w;
        }
        {
            const float4* p = (const float4*)(a1p + ka);
            float4 x0 = p[0], x1 = p[1];
            afr[1][0] = (_Float16)x0.x; afr[1][1] = (_Float16)x0.y;
            afr[1][2] = (_Float16)x0.z; afr[1][3] = (_Float16)x0.w;
            afr[1][4] = (_Float16)x1.x; afr[1][5] = (_Float16)x1.y;
            afr[1][6] = (_Float16)x1.z; afr[1][7] = (_Float16)x1.w;
        }
        f16x8 bfr[4];
#pragma unroll
        for (int nt = 0; nt < 4; nt++) {
            const float* bp = Wx + (long)ka * NN + (bn + wn + nt * 16 + l16);
#pragma unroll
            for (int jj = 0; jj < 8; jj++) bfr[nt][jj] = (_Float16)bp[(long)jj * NN];
        }
#pragma unroll
        for (int mt = 0; mt < 2; mt++)
#pragma unroll
            for (int nt = 0; nt < 4; nt++)
                acc[mt][nt] = MFMA16(afr[mt], bfr[nt], acc[mt][nt]);
    }
#pragma unroll
    for (int mt = 0; mt < 2; mt++) {
        int rowbase = bm + wm + mt * 16 + quad * 4;
#pragma unroll
        for (int nt = 0; nt < 4; nt++) {
            int col = bn + wn + nt * 16 + l16;
            float bias = bx[col];
#pragma unroll
            for (int r = 0; r < 4; r++) {
                int i = rowbase + r;
                int b = i >> 8, t = i & 255;          // T = 256
                xproj[((long)t * BB + b) * NN + col] = (_Float16)(acc[mt][nt][r] + bias);
            }
        }
    }
}

// ---------------- persistent GRU recurrence ----------------
// R10 = R9 (2147us, best) with ONE change: the read side.
//   R9's remaining 8.4us/step was dominated by the per-step agent-ACQUIRE
//   fence (buffer_inv): it wipes L1+L2, forcing h (8MB/step chip-wide) AND
//   the step's 390KB xproj to refill from LLC/HBM at miss latency inside
//   the serial step. Evidence: FETCH_SIZE 333MB = 3.3x the true read set.
// Change: DELETE the fence; h loads become sc0sc1 (LLC-direct, never stale)
//   via the 16-deep inline-asm register window with counted vmcnt(8/8/8/0)
//   -- the exact pipeline proven correct in R3/R6 (absmax 4.88e-4). x/out/
//   weights stay plain cached and now stay WARM across steps.
// vmcnt robustness: plain x loads interleaving before/inside the window can
//   only over-drain (extra completions), never under-drain the h window --
//   "<=N outstanding" keeps the NEWEST N, and any interleaved extra pushes
//   an h load into the completed set. Compiler's own waits for its loads
//   are satisfied because our q3 vmcnt(0) precedes all x uses.
// Registers: w pins re-split 64 AGPR + 32 VGPR (128V) + 64V window ~ 240V
//   total -> under the 256 encoding limit; no spill (R4's failure mode).
// Sync (unchanged from R9): write-through sc0sc1 h stores, barrier-drained;
//   RELAXED adds to 8 counters 64B apart; tid==0 pipelined 8-load spin.
__global__ __launch_bounds__(256, 1) void gru_kernel(
    const _Float16* __restrict__ xproj,   // [T][B][3U]
    const _Float16* __restrict__ WhF,     // fragment layout
    const float* __restrict__ hidden,     // [B][U] fp32 h0
    const float* __restrict__ bh,         // [3U]
    _Float16* __restrict__ hbuf,          // [2][B][U]
    u32* cnt,                             // 8 counters, 64B apart
    float* __restrict__ out) {            // [B][T][U] ++ [B][U]
    int tid  = threadIdx.x;
    int wave = tid >> 6, lane = tid & 63, quad = lane >> 4, l16 = lane & 15;
    int j  = blockIdx.x;
    int u  = j * 16 + l16;
    int b0 = wave * 16;

    float bhz = bh[u], bhr = bh[UU + u], bhh = bh[2 * UU + u];

    float hold[4];
#pragma unroll
    for (int r = 0; r < 4; r++) hold[r] = hidden[(long)(b0 + quad * 4 + r) * UU + u];

    // ---- whole per-WG weight slice into registers, ONCE (64 AGPR + 32 VGPR) ----
    const f16x8* WF = (const f16x8*)WhF + (long)j * 3 * 32 * 64 + lane;
    f16x8 w[96];                      // w[g*32+kb]
#pragma unroll
    for (int i = 0; i < 96; i++) w[i] = WF[(long)i * 64];
#pragma unroll
    for (int i = 0; i < 64; i++) asm volatile("" : "+a"(w[i]));
#pragma unroll
    for (int i = 64; i < 96; i++) asm volatile("" : "+v"(w[i]));

#pragma unroll 1
    for (int t = 0; t < TT; t++) {
        // ---- x loads: plain cached (L2 stays warm now - no fence) ----
        const _Float16* xp = xproj + (long)t * BB * NN;
        float xzv[4], xrv[4], xhv[4];
#pragma unroll
        for (int r = 0; r < 4; r++) {
            const _Float16* p = xp + (long)(b0 + quad * 4 + r) * NN + u;
            xzv[r] = (float)p[0]; xrv[r] = (float)p[UU]; xhv[r] = (float)p[2 * UU];
        }

        // ---- h: LLC-direct sc0sc1 loads, 16-deep window, counted vmcnt ----
        const _Float16* h = hbuf + (long)(t & 1) * BB * UU
                                 + (long)(b0 + l16) * UU + quad * 8;
        f16x8 hf[16];
#pragma unroll
        for (int kb = 0; kb < 16; kb++)
            asm volatile("global_load_dwordx4 %0, %1, off sc0 sc1"
                         : "=v"(hf[kb]) : "v"(h + (long)kb * 32));

        f32x4 az = {0.f, 0.f, 0.f, 0.f}, ar = az, ah = az;
#pragma unroll
        for (int q = 0; q < 4; q++) {
            if (q < 3) asm volatile("s_waitcnt vmcnt(8)" ::: "memory");
            else       asm volatile("s_waitcnt vmcnt(0)" ::: "memory");
            __builtin_amdgcn_sched_barrier(0);   // rule #18: MFMAs stay below the wait
#pragma unroll
            for (int i = 0; i < 8; i++) {
                int kb = q * 8 + i;
                f16x8 afr = hf[kb & 15];
                az = MFMA16(afr, w[kb],      az);
                ar = MFMA16(afr, w[32 + kb], ar);
                ah = MFMA16(afr, w[64 + kb], ah);
            }
            if (q < 2) {   // refill consumed slots with kb 16..31
#pragma unroll
                for (int i = 0; i < 8; i++) {
                    int kb2 = 16 + q * 8 + i;
                    asm volatile("global_load_dwordx4 %0, %1, off sc0 sc1"
                                 : "=v"(hf[kb2 & 15]) : "v"(h + (long)kb2 * 32));
                }
            }
        }

        // ---- gates; write-through h stores (sc0sc1); plain out stores ----
        _Float16* hw = hbuf + (long)((t + 1) & 1) * BB * UU;
#pragma unroll
        for (int r = 0; r < 4; r++) {
            int b = b0 + quad * 4 + r;
            float z  = 1.f / (1.f + expf(-(xzv[r] + az[r] + bhz)));
            float rr = 1.f / (1.f + expf(-(xrv[r] + ar[r] + bhr)));
            float cd = tanhf(xhv[r] + rr * (ah[r] + bhh));
            float hn = z * hold[r] + (1.f - z) * cd;
            hold[r] = hn;
            out[(long)b * TT * UU + (long)t * UU + u] = hn;
            u32 hv = (u32)__builtin_bit_cast(unsigned short, (_Float16)hn);
            asm volatile("global_store_short %0, %1, off sc0 sc1"
                         :: "v"(hw + (long)b * UU + u), "v"(hv) : "memory");
        }

        if (t != TT - 1) {
            __syncthreads();   // drains each wave's vmcnt -> h at LLC
            if (tid == 0) {
                // RELAXED add (no wbl2): store visibility already ensured
                __hip_atomic_fetch_add(cnt + (j >> 3) * 16, 1u,
                                       __ATOMIC_RELAXED, __HIP_MEMORY_SCOPE_AGENT);
                u32 tgt = 8u * (u32)(t + 1);
                for (;;) {
                    u32 c0, c1, c2, c3, c4, c5, c6, c7;
                    asm volatile(
                        "global_load_dword %0, %8, off sc0 sc1\n\t"
                        "global_load_dword %1, %8, off offset:64 sc0 sc1\n\t"
                        "global_load_dword %2, %8, off offset:128 sc0 sc1\n\t"
                        "global_load_dword %3, %8, off offset:192 sc0 sc1\n\t"
                        "global_load_dword %4, %8, off offset:256 sc0 sc1\n\t"
                        "global_load_dword %5, %8, off offset:320 sc0 sc1\n\t"
                        "global_load_dword %6, %8, off offset:384 sc0 sc1\n\t"
                        "global_load_dword %7, %8, off offset:448 sc0 sc1\n\t"
                        "s_waitcnt vmcnt(0)"
                        : "=&v"(c0), "=&v"(c1), "=&v"(c2), "=&v"(c3),
                          "=&v"(c4), "=&v"(c5), "=&v"(c6), "=&v"(c7)
                        : "v"(cnt) : "memory");
                    if (c0 >= tgt && c1 >= tgt && c2 >= tgt && c3 >= tgt &&
                        c4 >= tgt && c5 >= tgt && c6 >= tgt && c7 >= tgt) break;
                    __builtin_amdgcn_s_sleep(1);
                }
                // NO acquire fence: h reads are sc0sc1 (LLC-direct), caches stay warm
            }
            __syncthreads();
        }
    }
#pragma unroll
    for (int r = 0; r < 4; r++) {
        int b = b0 + quad * 4 + r;
        out[(long)BB * TT * UU + (long)b * UU + u] = hold[r];
    }
}

// ---------------- launch ----------------
extern "C" void kernel_launch(void* const* d_in, const int* in_sizes, int n_in,
                              void* d_out, int out_size, void* d_ws, size_t ws_size,
                              hipStream_t stream) {
    const int*   tokens = (const int*)d_in[0];
    const float* hidden = (const float*)d_in[1];
    const float* emb    = (const float*)d_in[2];
    const float* Wx     = (const float*)d_in[3];
    const float* bx     = (const float*)d_in[4];
    const float* Wh     = (const float*)d_in[5];
    const float* bh     = (const float*)d_in[6];
    float* out = (float*)d_out;

    char* ws = (char*)d_ws;
    _Float16* xproj = (_Float16*)(ws);                  // 100663296 B
    _Float16* WhF   = (_Float16*)(ws + 100663296L);     //   6291456 B
    _Float16* hbuf  = (_Float16*)(ws + 106954752L);     //    262144 B
    u32*      cnt   = (u32*)(ws + 107216896L);          //     512 B (8 ctrs, 64B apart)
    if (ws_size < 107217408UL) return;

    hipMemsetAsync(cnt, 0, 512, stream);
    prep_whf<<<1536, 256, 0, stream>>>(Wh, WhF);
    prep_h0<<<256, 256, 0, stream>>>(hidden, hbuf);
    proj_kernel<<<dim3(256, 24), 256, 0, stream>>>(tokens, emb, Wx, bx, xproj);
    gru_kernel<<<64, 256, 0, stream>>>(xproj, WhF, hidden, bh, hbuf, cnt, out);
}

// Round 9
// 2218.614 us; speedup vs baseline: 2.6437x; 1.1211x over previous
//
#include <hip/hip_runtime.h>
#include <cstdint>

typedef _Float16 f16x8 __attribute__((ext_vector_type(8)));
typedef float    f32x4 __attribute__((ext_vector_type(4)));
typedef unsigned int u32;
typedef u32      u32x4 __attribute__((ext_vector_type(4)));

#define BB 64
#define TT 256
#define EE 512
#define UU 1024
#define NN 3072   // 3*U

#define MFMA16(a, b, c) __builtin_amdgcn_mfma_f32_16x16x32_f16((a), (b), (c), 0, 0, 0)

// ---------------- prep: Wh -> f16 MFMA B-fragment layout ----------------
// WhF[((j*3+g)*32 + kb)*64 + lane][jj] = f16(Wh[kb*32 + quad*8 + jj][g*1024 + j*16 + l16])
__global__ __launch_bounds__(256) void prep_whf(const float* __restrict__ Wh,
                                                _Float16* __restrict__ WhF) {
    int tid  = blockIdx.x * 256 + threadIdx.x;   // 0..393215
    int col8 = tid % 384;                        // group of 8 consecutive columns
    int k    = tid / 384;                        // 0..1023
    int kb = k >> 5, quad = (k >> 3) & 3, jj = k & 7;
    const float* src = Wh + (long)k * NN + col8 * 8;
#pragma unroll
    for (int i = 0; i < 8; i++) {
        int n   = col8 * 8 + i;
        int g   = n >> 10;
        int nl  = n & 1023;
        int j   = nl >> 4, l16 = nl & 15;
        int lane = quad * 16 + l16;
        WhF[((((j * 3 + g) * 32 + kb) * 64 + lane) << 3) + jj] = (_Float16)src[i];
    }
}

__global__ __launch_bounds__(256) void prep_h0(const float* __restrict__ h0,
                                               _Float16* __restrict__ hbuf) {
    int i = blockIdx.x * 256 + threadIdx.x;      // 0..65535
    hbuf[i] = (_Float16)h0[i];   // kernel-end writeback -> visible to LLC-direct reads
}

// ---------------- embed + input projection GEMM (f16 MFMA) ----------------
__global__ __launch_bounds__(256) void proj_kernel(
    const int* __restrict__ tokens, const float* __restrict__ emb,
    const float* __restrict__ Wx, const float* __restrict__ bx,
    _Float16* __restrict__ xproj) {
    int tid  = threadIdx.x;
    int wave = tid >> 6, lane = tid & 63, quad = lane >> 4, l16 = lane & 15;
    int bm = blockIdx.x * 64;           // M offset (i = b*T+t)
    int bn = blockIdx.y * 128;          // N offset
    int wm = (wave & 1) * 32, wn = (wave >> 1) * 64;

    int row0 = bm + wm + l16;
    const float* a0p = emb + (long)tokens[row0] * EE;
    const float* a1p = emb + (long)tokens[row0 + 16] * EE;

    f32x4 acc[2][4];
#pragma unroll
    for (int mt = 0; mt < 2; mt++)
#pragma unroll
        for (int nt = 0; nt < 4; nt++) { f32x4 z = {0.f, 0.f, 0.f, 0.f}; acc[mt][nt] = z; }

#pragma unroll 2
    for (int k0 = 0; k0 < EE; k0 += 32) {
        int ka = k0 + quad * 8;
        f16x8 afr[2];
        {
            const float4* p = (const float4*)(a0p + ka);
            float4 x0 = p[0], x1 = p[1];
            afr[0][0] = (_Float16)x0.x; afr[0][1] = (_Float16)x0.y;
            afr[0][2] = (_Float16)x0.z; afr[0][3] = (_Float16)x0.w;
            afr[0][4] = (_Float16)x1.x; afr[0][5] = (_Float16)x1.y;
            afr[0][6] = (_Float16)x1.z; afr[0][7] = (_Float16)x1.w;
        }
        {
            const float4* p = (const float4*)(a1p + ka);
            float4 x0 = p[0], x1 = p[1];
            afr[1][0] = (_Float16)x0.x; afr[1][1] = (_Float16)x0.y;
            afr[1][2] = (_Float16)x0.z; afr[1][3] = (_Float16)x0.w;
            afr[1][4] = (_Float16)x1.x; afr[1][5] = (_Float16)x1.y;
            afr[1][6] = (_Float16)x1.z; afr[1][7] = (_Float16)x1.w;
        }
        f16x8 bfr[4];
#pragma unroll
        for (int nt = 0; nt < 4; nt++) {
            const float* bp = Wx + (long)ka * NN + (bn + wn + nt * 16 + l16);
#pragma unroll
            for (int jj = 0; jj < 8; jj++) bfr[nt][jj] = (_Float16)bp[(long)jj * NN];
        }
#pragma unroll
        for (int mt = 0; mt < 2; mt++)
#pragma unroll
            for (int nt = 0; nt < 4; nt++)
                acc[mt][nt] = MFMA16(afr[mt], bfr[nt], acc[mt][nt]);
    }
#pragma unroll
    for (int mt = 0; mt < 2; mt++) {
        int rowbase = bm + wm + mt * 16 + quad * 4;
#pragma unroll
        for (int nt = 0; nt < 4; nt++) {
            int col = bn + wn + nt * 16 + l16;
            float bias = bx[col];
#pragma unroll
            for (int r = 0; r < 4; r++) {
                int i = rowbase + r;
                int b = i >> 8, t = i & 255;          // T = 256
                xproj[((long)t * BB + b) * NN + col] = (_Float16)(acc[mt][nt][r] + bias);
            }
        }
    }
}

// ---------------- persistent GRU recurrence ----------------
// R11 = R10 (2046us best) with two surgical changes:
//  1. SYNC: the 8x8 atomic-RMW counter tree (8-deep same-line RMW chains,
//     each RMW ~150-300cy serialized at LLC => ~1.5-2us/step) is replaced by
//     per-WG FLAG STORES (zero write contention: flag[j] at (j>>3)*64 +
//     (j&7)*4, 8 flags/line over 8 lines) + a 16-lane poll (one dwordx4 per
//     lane covers 4 flags; 16 parallel transactions/round). Induction as
//     R9/R10: flag=t+1 published only after __syncthreads drained this WG's
//     write-through h stores to LLC; all flags >= t+1 => h_{t+1} complete
//     AND every WG finished reading h_t (reads precede stores) => 2-slot
//     overwrite safe. Skew <= 1 step; monotone >= compare handles it.
//     No atomics, no fences anywhere.
//  2. LOCALITY: XCD-aware j remap, j = (bi&7)<<3 | bi>>3. Round-robin
//     dispatch puts blocks bi = x, x+8, .. x+56 on XCD x; they now own
//     CONTIGUOUS j => the xproj/out cache lines shared by 4 adjacent j are
//     fetched into ONE XCD's L2 instead of 4 (FETCH_SIZE was 333MB vs the
//     ~106MB true read set across R2-R10 — xproj line amplification).
// Everything else identical to R10: h loads sc0sc1 LLC-direct via 16-deep
// counted-vmcnt window; h stores write-through sc0sc1; weights 64 AGPR +
// 32 VGPR pinned; x/out plain cached.
__global__ __launch_bounds__(256, 1) void gru_kernel(
    const _Float16* __restrict__ xproj,   // [T][B][3U]
    const _Float16* __restrict__ WhF,     // fragment layout
    const float* __restrict__ hidden,     // [B][U] fp32 h0
    const float* __restrict__ bh,         // [3U]
    _Float16* __restrict__ hbuf,          // [2][B][U]
    u32* cnt,                             // 64 flags: (j>>3)*16 + (j&7) u32s
    float* __restrict__ out) {            // [B][T][U] ++ [B][U]
    int tid  = threadIdx.x;
    int wave = tid >> 6, lane = tid & 63, quad = lane >> 4, l16 = lane & 15;
    int j  = ((blockIdx.x & 7) << 3) | (blockIdx.x >> 3);   // XCD-contiguous u-slices
    int u  = j * 16 + l16;
    int b0 = wave * 16;

    float bhz = bh[u], bhr = bh[UU + u], bhh = bh[2 * UU + u];

    float hold[4];
#pragma unroll
    for (int r = 0; r < 4; r++) hold[r] = hidden[(long)(b0 + quad * 4 + r) * UU + u];

    // ---- whole per-WG weight slice into registers, ONCE (64 AGPR + 32 VGPR) ----
    const f16x8* WF = (const f16x8*)WhF + (long)j * 3 * 32 * 64 + lane;
    f16x8 w[96];                      // w[g*32+kb]
#pragma unroll
    for (int i = 0; i < 96; i++) w[i] = WF[(long)i * 64];
#pragma unroll
    for (int i = 0; i < 64; i++) asm volatile("" : "+a"(w[i]));
#pragma unroll
    for (int i = 64; i < 96; i++) asm volatile("" : "+v"(w[i]));

    u32* fstore = cnt + ((j >> 3) << 4) + (j & 7);          // own flag (own 4B slot)
    const u32* fpoll = cnt + ((lane >> 1) << 4) + ((lane & 1) << 2);  // lanes 0..15: 4 flags each

#pragma unroll 1
    for (int t = 0; t < TT; t++) {
        // ---- x loads: plain cached; complete under the h window's vmcnt(0) ----
        const _Float16* xp = xproj + (long)t * BB * NN;
        float xzv[4], xrv[4], xhv[4];
#pragma unroll
        for (int r = 0; r < 4; r++) {
            const _Float16* p = xp + (long)(b0 + quad * 4 + r) * NN + u;
            xzv[r] = (float)p[0]; xrv[r] = (float)p[UU]; xhv[r] = (float)p[2 * UU];
        }

        // ---- h: LLC-direct sc0sc1 loads, 16-deep window, counted vmcnt ----
        const _Float16* h = hbuf + (long)(t & 1) * BB * UU
                                 + (long)(b0 + l16) * UU + quad * 8;
        f16x8 hf[16];
#pragma unroll
        for (int kb = 0; kb < 16; kb++)
            asm volatile("global_load_dwordx4 %0, %1, off sc0 sc1"
                         : "=v"(hf[kb]) : "v"(h + (long)kb * 32));

        f32x4 az = {0.f, 0.f, 0.f, 0.f}, ar = az, ah = az;
#pragma unroll
        for (int q = 0; q < 4; q++) {
            if (q < 3) asm volatile("s_waitcnt vmcnt(8)" ::: "memory");
            else       asm volatile("s_waitcnt vmcnt(0)" ::: "memory");
            __builtin_amdgcn_sched_barrier(0);   // rule #18: MFMAs stay below the wait
#pragma unroll
            for (int i = 0; i < 8; i++) {
                int kb = q * 8 + i;
                f16x8 afr = hf[kb & 15];
                az = MFMA16(afr, w[kb],      az);
                ar = MFMA16(afr, w[32 + kb], ar);
                ah = MFMA16(afr, w[64 + kb], ah);
            }
            if (q < 2) {   // refill consumed slots with kb 16..31
#pragma unroll
                for (int i = 0; i < 8; i++) {
                    int kb2 = 16 + q * 8 + i;
                    asm volatile("global_load_dwordx4 %0, %1, off sc0 sc1"
                                 : "=v"(hf[kb2 & 15]) : "v"(h + (long)kb2 * 32));
                }
            }
        }

        // ---- gates; write-through h stores (sc0sc1); plain out stores ----
        _Float16* hw = hbuf + (long)((t + 1) & 1) * BB * UU;
#pragma unroll
        for (int r = 0; r < 4; r++) {
            int b = b0 + quad * 4 + r;
            float z  = 1.f / (1.f + expf(-(xzv[r] + az[r] + bhz)));
            float rr = 1.f / (1.f + expf(-(xrv[r] + ar[r] + bhr)));
            float cd = tanhf(xhv[r] + rr * (ah[r] + bhh));
            float hn = z * hold[r] + (1.f - z) * cd;
            hold[r] = hn;
            out[(long)b * TT * UU + (long)t * UU + u] = hn;
            u32 hv = (u32)__builtin_bit_cast(unsigned short, (_Float16)hn);
            asm volatile("global_store_short %0, %1, off sc0 sc1"
                         :: "v"(hw + (long)b * UU + u), "v"(hv) : "memory");
        }

        if (t != TT - 1) {
            __syncthreads();   // drains each wave's vmcnt -> this WG's h at LLC
            if (wave == 0 && lane < 16) {
                if (lane == 0)
                    asm volatile("global_store_dword %0, %1, off sc0 sc1"
                                 :: "v"(fstore), "v"((u32)(t + 1)) : "memory");
                u32 tgt = (u32)(t + 1);
                for (;;) {
                    u32x4 fv;
                    asm volatile("global_load_dwordx4 %0, %1, off sc0 sc1\n\t"
                                 "s_waitcnt vmcnt(0)"
                                 : "=v"(fv) : "v"(fpoll) : "memory");
                    bool ok = (fv[0] >= tgt) & (fv[1] >= tgt) &
                              (fv[2] >= tgt) & (fv[3] >= tgt);
                    if (__all(ok)) break;      // over the 16 active lanes
                    __builtin_amdgcn_s_sleep(1);
                }
            }
            __syncthreads();
        }
    }
#pragma unroll
    for (int r = 0; r < 4; r++) {
        int b = b0 + quad * 4 + r;
        out[(long)BB * TT * UU + (long)b * UU + u] = hold[r];
    }
}

// ---------------- launch ----------------
extern "C" void kernel_launch(void* const* d_in, const int* in_sizes, int n_in,
                              void* d_out, int out_size, void* d_ws, size_t ws_size,
                              hipStream_t stream) {
    const int*   tokens = (const int*)d_in[0];
    const float* hidden = (const float*)d_in[1];
    const float* emb    = (const float*)d_in[2];
    const float* Wx     = (const float*)d_in[3];
    const float* bx     = (const float*)d_in[4];
    const float* Wh     = (const float*)d_in[5];
    const float* bh     = (const float*)d_in[6];
    float* out = (float*)d_out;

    char* ws = (char*)d_ws;
    _Float16* xproj = (_Float16*)(ws);                  // 100663296 B
    _Float16* WhF   = (_Float16*)(ws + 100663296L);     //   6291456 B
    _Float16* hbuf  = (_Float16*)(ws + 106954752L);     //    262144 B
    u32*      cnt   = (u32*)(ws + 107216896L);          //     512 B (64 flags, 8/line)
    if (ws_size < 107217408UL) return;

    hipMemsetAsync(cnt, 0, 512, stream);
    prep_whf<<<1536, 256, 0, stream>>>(Wh, WhF);
    prep_h0<<<256, 256, 0, stream>>>(hidden, hbuf);
    proj_kernel<<<dim3(256, 24), 256, 0, stream>>>(tokens, emb, Wx, bx, xproj);
    gru_kernel<<<64, 256, 0, stream>>>(xproj, WhF, hidden, bh, hbuf, cnt, out);
}